// Round 5
// baseline (445.938 us; speedup 1.0000x reference)
//
#include <hip/hip_runtime.h>
#include <hip/hip_bf16.h>
#include <cstdint>

#define VOCAB  50001
#define EMBED  64
#define HIDDEN 100
#define TSTEPS 512
#define BATCH  2048

typedef short bf16x8 __attribute__((ext_vector_type(8)));
typedef float f32x4  __attribute__((ext_vector_type(4)));

constexpr int RB = 16;               // batch rows per block
constexpr int KP = 128;              // padded K (hidden) for MFMA
constexpr int UP = 112;              // padded units (M)
constexpr int NBLK = BATCH / RB;     // 128 blocks

constexpr size_t WHH_BYTES = (size_t)UP * KP * 2;      // 28672 per half
constexpr size_t P_OFF     = 2 * WHH_BYTES;            // 57344
constexpr size_t P_BYTES   = (size_t)VOCAB * HIDDEN * 4;
constexpr size_t WS_NEED   = P_OFF + P_BYTES;

__device__ __forceinline__ float fast_tanh(float x) {
  const float e = __expf(2.0f * x);
  return 1.0f - 2.0f * __builtin_amdgcn_rcpf(e + 1.0f);
}
__device__ __forceinline__ unsigned cvt_pk_bf16(float a, float b) {
  unsigned r;
  asm("v_cvt_pk_bf16_f32 %0, %1, %2" : "=v"(r) : "v"(a), "v"(b));
  return r;
}
__device__ __forceinline__ f32x4 zf4() { f32x4 z = {0.f, 0.f, 0.f, 0.f}; return z; }

// Barrier with LDS-only drain: skips the vmcnt(0) that __syncthreads would
// emit, so in-flight P-seed gathers (lane-private) never stall the barrier.
__device__ __forceinline__ void lds_barrier() {
  asm volatile("s_waitcnt lgkmcnt(0)\n\ts_barrier" ::: "memory");
}

#define MFMA16(A,B,C) __builtin_amdgcn_mfma_f32_16x16x32_bf16((A),(B),(C),0,0,0)

// ---------------- P[v][j] = W_ih[j,:]·table[v,:] + b_ih[j] + b_hh[j] -----------
__global__ __launch_bounds__(128) void proj_kernel(
    const float* __restrict__ table, const float* __restrict__ Wih,
    const float* __restrict__ bih, const float* __restrict__ bhh,
    float* __restrict__ P)
{
  constexpr int VPB = 16;
  __shared__ float e[VPB][EMBED];
  const int vbase = blockIdx.x * VPB;
  const int tid = threadIdx.x;
  #pragma unroll
  for (int r = 0; r < VPB * EMBED / 128; ++r) {
    const int el = tid + 128 * r;
    const int v  = vbase + (el >> 6);
    e[el >> 6][el & 63] = (v < VOCAB) ? table[(size_t)v * EMBED + (el & 63)] : 0.f;
  }
  __syncthreads();

  const int j = (tid < HIDDEN) ? tid : HIDDEN - 1;
  float w[EMBED];
  #pragma unroll
  for (int k = 0; k < EMBED; k += 4) {
    const float4 t4 = *reinterpret_cast<const float4*>(&Wih[j * EMBED + k]);
    w[k] = t4.x; w[k+1] = t4.y; w[k+2] = t4.z; w[k+3] = t4.w;
  }
  const float bias = bih[j] + bhh[j];

  for (int r = 0; r < VPB; ++r) {
    const int v = vbase + r;
    if (v >= VOCAB) break;
    float acc = bias;
    #pragma unroll
    for (int k = 0; k < EMBED; k += 4) {
      const float4 ev = *reinterpret_cast<const float4*>(&e[r][k]);
      acc += w[k]*ev.x + w[k+1]*ev.y + w[k+2]*ev.z + w[k+3]*ev.w;
    }
    if (tid < HIDDEN) P[(size_t)v * HIDDEN + tid] = acc;
  }
}

// ---------------- Whh -> split-bf16 padded [UP][KP] (hi, lo) -------------------
__global__ __launch_bounds__(256) void prep_whh(
    const float* __restrict__ Whh, unsigned short* __restrict__ hi,
    unsigned short* __restrict__ lo)
{
  const int i = blockIdx.x * 256 + threadIdx.x;
  if (i >= UP * KP) return;
  const int u = i >> 7, k = i & (KP - 1);
  const float v = (u < HIDDEN && k < HIDDEN) ? Whh[u * HIDDEN + k] : 0.f;
  const unsigned b = __float_as_uint(v);
  const unsigned h16 = (b + 0x7FFFu + ((b >> 16) & 1u)) >> 16;
  const float hf = __uint_as_float(h16 << 16);
  const float r = v - hf;
  const unsigned rb = __float_as_uint(r);
  const unsigned l16 = (rb + 0x7FFFu + ((rb >> 16) & 1u)) >> 16;
  hi[i] = (unsigned short)h16;
  lo[i] = (unsigned short)l16;
}

// ---------------- MFMA recurrence: 16 rows/block, 4 waves ----------------------
// G^T[UP][16] = WhhP[UP][KP] x hT[KP][16]  per step; D frag: unit=(l>>4)*4+r+16*mt,
// row=l&15. A frag: unit=mt*16+(l&15), k-consecutive. B frag: h[row=l&15][k-consec].
__global__ __launch_bounds__(256, 1)
void rnn_mfma_kernel(const int* __restrict__ x, const unsigned char* __restrict__ ws,
                     const float* __restrict__ fcW, const float* __restrict__ fcb,
                     float* __restrict__ out)
{
  __shared__ __align__(16) unsigned char hbuf[2][2][4096]; // [buf][hi/lo][16 rows][128 k] bf16
  __shared__ int idx_lds[TSTEPS][RB];
  __shared__ float red[64];

  const int tid = threadIdx.x;
  const int w   = tid >> 6;
  const int l   = tid & 63;
  const int row = l & 15;
  const int g   = l >> 4;
  const int row0 = blockIdx.x * RB;
  const unsigned swz = (unsigned)((row & 7) << 4);

  // zero h buffers (doubles as h0 = 0)
  {
    uint4* hz = reinterpret_cast<uint4*>(&hbuf[0][0][0]);
    #pragma unroll
    for (int i = 0; i < 4; ++i) hz[tid + 256 * i] = make_uint4(0u, 0u, 0u, 0u);
  }
  // stage x indices transposed: idx_lds[t][r]
  {
    const int r = tid >> 4, tl = tid & 15;
    const int* __restrict__ xr = x + (size_t)(row0 + r) * TSTEPS;
    for (int c = 0; c < TSTEPS / 16; ++c) {
      const int t = tl + 16 * c;
      idx_lds[t][r] = xr[t];
    }
  }

  const unsigned char* __restrict__ WH = ws;
  const unsigned char* __restrict__ WL = ws + WHH_BYTES;
  const float* __restrict__ Pb = reinterpret_cast<const float*>(ws + P_OFF);

  const int  mt0  = w;
  const bool has2 = (w < 3);
  const int  mt1  = has2 ? (w + 4) : 0;

  // loop-invariant A fragments in registers (Whh split)
  bf16x8 whi0[4], wlo0[4], whi1[4], wlo1[4];
  #pragma unroll
  for (int kt = 0; kt < 4; ++kt) {
    const unsigned off0 = (unsigned)(mt0 * 16 + row) * 256u + (unsigned)(kt * 64 + g * 16);
    whi0[kt] = *reinterpret_cast<const bf16x8*>(WH + off0);
    wlo0[kt] = *reinterpret_cast<const bf16x8*>(WL + off0);
    const unsigned off1 = (unsigned)(mt1 * 16 + row) * 256u + (unsigned)(kt * 64 + g * 16);
    whi1[kt] = *reinterpret_cast<const bf16x8*>(WH + off1);
    wlo1[kt] = *reinterpret_cast<const bf16x8*>(WL + off1);
  }

  const int  useed0 = mt0 * 16 + g * 4;          // <= 60, always valid
  const int  useed1 = mt1 * 16 + g * 4;
  const bool ok1 = has2 && (useed1 <= 96);       // mt=6,g>0 are pure padding

  __syncthreads();

  // seed prefetch (depth 2): SA for even steps, SB for odd
  f32x4 SA[2], SB[2];
  {
    const int x0 = idx_lds[0][row];
    const int x1 = idx_lds[1][row];
    SA[0] = *reinterpret_cast<const f32x4*>(Pb + (size_t)x0 * HIDDEN + useed0);
    SB[0] = *reinterpret_cast<const f32x4*>(Pb + (size_t)x1 * HIDDEN + useed0);
    SA[1] = ok1 ? *reinterpret_cast<const f32x4*>(Pb + (size_t)x0 * HIDDEN + useed1) : zf4();
    SB[1] = ok1 ? *reinterpret_cast<const f32x4*>(Pb + (size_t)x1 * HIDDEN + useed1) : zf4();
  }

  auto body = [&](int t, const unsigned char* hbR, unsigned char* hbW, f32x4 (&S)[2]) {
    // B fragments first (critical path): h hi/lo, XOR-swizzled rows
    bf16x8 bhi[4], blo[4];
    #pragma unroll
    for (int kt = 0; kt < 4; ++kt) {
      const unsigned off = ((unsigned)(row * 256 + kt * 64 + g * 16)) ^ swz;
      bhi[kt] = *reinterpret_cast<const bf16x8*>(hbR + off);
      blo[kt] = *reinterpret_cast<const bf16x8*>(hbR + 4096 + off);
    }
    // issue seed gathers for t+2 NOW -> ~2 full bodies of slack before use;
    // the lgkmcnt-only barrier never drains them.
    const int tn = (t + 2 < TSTEPS) ? t + 2 : TSTEPS - 1;
    const int xt = idx_lds[tn][row];
    const f32x4 Sn0 = *reinterpret_cast<const f32x4*>(Pb + (size_t)xt * HIDDEN + useed0);
    f32x4 Sn1 = zf4();
    if (ok1) Sn1 = *reinterpret_cast<const f32x4*>(Pb + (size_t)xt * HIDDEN + useed1);

    // tile 0: 3 split products on independent accumulators
    f32x4 a1 = S[0], a2 = zf4(), a3 = zf4();
    #pragma unroll
    for (int kt = 0; kt < 4; ++kt) {
      a1 = MFMA16(whi0[kt], bhi[kt], a1);
      a2 = MFMA16(whi0[kt], blo[kt], a2);
      a3 = MFMA16(wlo0[kt], bhi[kt], a3);
    }
    const f32x4 d0 = (a1 + a2) + a3;
    f32x4 d1 = zf4();
    if (has2) {
      f32x4 c1 = S[1], c2 = zf4(), c3 = zf4();
      #pragma unroll
      for (int kt = 0; kt < 4; ++kt) {
        c1 = MFMA16(whi1[kt], bhi[kt], c1);
        c2 = MFMA16(whi1[kt], blo[kt], c2);
        c3 = MFMA16(wlo1[kt], bhi[kt], c3);
      }
      d1 = (c1 + c2) + c3;
    }
    // tanh -> split bf16 -> LDS (tile 0)
    {
      const float t0 = fast_tanh(d0[0]), t1v = fast_tanh(d0[1]);
      const float t2 = fast_tanh(d0[2]), t3v = fast_tanh(d0[3]);
      const unsigned ph01 = cvt_pk_bf16(t0, t1v), ph23 = cvt_pk_bf16(t2, t3v);
      const float h0f = __uint_as_float(ph01 << 16), h1f = __uint_as_float(ph01 & 0xFFFF0000u);
      const float h2f = __uint_as_float(ph23 << 16), h3f = __uint_as_float(ph23 & 0xFFFF0000u);
      const unsigned pl01 = cvt_pk_bf16(t0 - h0f, t1v - h1f);
      const unsigned pl23 = cvt_pk_bf16(t2 - h2f, t3v - h3f);
      const unsigned off = ((unsigned)(row * 256 + useed0 * 2)) ^ swz;
      *reinterpret_cast<uint2*>(hbW + off)        = make_uint2(ph01, ph23);
      *reinterpret_cast<uint2*>(hbW + 4096 + off) = make_uint2(pl01, pl23);
    }
    if (ok1) {
      const float t0 = fast_tanh(d1[0]), t1v = fast_tanh(d1[1]);
      const float t2 = fast_tanh(d1[2]), t3v = fast_tanh(d1[3]);
      const unsigned ph01 = cvt_pk_bf16(t0, t1v), ph23 = cvt_pk_bf16(t2, t3v);
      const float h0f = __uint_as_float(ph01 << 16), h1f = __uint_as_float(ph01 & 0xFFFF0000u);
      const float h2f = __uint_as_float(ph23 << 16), h3f = __uint_as_float(ph23 & 0xFFFF0000u);
      const unsigned pl01 = cvt_pk_bf16(t0 - h0f, t1v - h1f);
      const unsigned pl23 = cvt_pk_bf16(t2 - h2f, t3v - h3f);
      const unsigned off = ((unsigned)(row * 256 + useed1 * 2)) ^ swz;
      *reinterpret_cast<uint2*>(hbW + off)        = make_uint2(ph01, ph23);
      *reinterpret_cast<uint2*>(hbW + 4096 + off) = make_uint2(pl01, pl23);
    }
    // rotate seeds (SSA rename; vmcnt wait lands at next use, 2 bodies away)
    S[0] = Sn0;
    if (ok1) S[1] = Sn1;
    lds_barrier();
  };

  for (int t = 0; t < TSTEPS; t += 2) {
    body(t,     &hbuf[0][0][0], &hbuf[1][0][0], SA);
    body(t + 1, &hbuf[1][0][0], &hbuf[0][0][0], SB);
  }

  // FC + sigmoid (final h is in hbuf[0])
  if (w == 0) {
    const unsigned char* hbF  = &hbuf[0][0][0];
    const unsigned char* hbFl = &hbuf[0][1][0];
    float part = 0.f;
    for (int i = 0; i < 25; ++i) {
      const int u = g * 25 + i;
      const unsigned off = ((unsigned)(row * 256 + u * 2)) ^ swz;
      const unsigned short vh = *reinterpret_cast<const unsigned short*>(hbF + off);
      const unsigned short vl = *reinterpret_cast<const unsigned short*>(hbFl + off);
      const float hv = __uint_as_float((unsigned)vh << 16) +
                       __uint_as_float((unsigned)vl << 16);
      part += hv * fcW[u];
    }
    red[l] = part;
  }
  __syncthreads();
  if (tid < RB) {
    const float s = red[tid] + red[tid + 16] + red[tid + 32] + red[tid + 48] + fcb[0];
    out[row0 + tid] = 1.0f / (1.0f + __expf(-s));
  }
}

// ---------------- fallback: exact fp32 wave kernel -----------------------------
__global__ __launch_bounds__(64)
__attribute__((amdgpu_waves_per_eu(2, 2)))
void rnn_wave_kernel(
    const int* __restrict__ x, const float* __restrict__ P,
    const float* __restrict__ Whh,
    const float* __restrict__ fcW, const float* __restrict__ fcb,
    float* __restrict__ out)
{
  __shared__ float h_lds[2][112];
  const int row = blockIdx.x;
  const int l = threadIdx.x;
  const int u0 = l;
  const bool m1 = (l < HIDDEN - 64);
  const int u1 = m1 ? (64 + l) : (HIDDEN - 1);

  float w0[HIDDEN], w1[HIDDEN];
  #pragma unroll
  for (int k = 0; k < HIDDEN; k += 4) {
    const float4 a = *reinterpret_cast<const float4*>(&Whh[u0 * HIDDEN + k]);
    w0[k] = a.x; w0[k+1] = a.y; w0[k+2] = a.z; w0[k+3] = a.w;
    const float4 b = *reinterpret_cast<const float4*>(&Whh[u1 * HIDDEN + k]);
    w1[k] = b.x; w1[k+1] = b.y; w1[k+2] = b.z; w1[k+3] = b.w;
  }
  const float fw0 = fcW[u0];
  const float fw1 = m1 ? fcW[u1] : 0.f;

  h_lds[0][l] = 0.f;
  h_lds[0][l + 48] = 0.f;

  const int* __restrict__ xrow = x + (size_t)row * TSTEPS;
  const int i0 = xrow[0];
  float xp0 = P[i0 * HIDDEN + u0];
  float xp1 = P[i0 * HIDDEN + u1];
  int i_nx = xrow[1];

  float h0 = 0.f, h1 = 0.f;
  for (int t = 0; t < TSTEPS; ++t) {
    const int cur = t & 1, nxt = cur ^ 1;
    const float* __restrict__ Prow = P + i_nx * HIDDEN;
    const float xp0n = Prow[u0];
    const float xp1n = Prow[u1];
    i_nx = (t + 2 < TSTEPS) ? xrow[t + 2] : 0;

    float a0 = xp0, b0 = 0.f, a1v = xp1, b1 = 0.f;
    const float4* __restrict__ hb = reinterpret_cast<const float4*>(&h_lds[cur][0]);
    #pragma unroll
    for (int gq = 0; gq < HIDDEN / 4; ++gq) {
      const float4 hv = hb[gq];
      const int k = 4 * gq;
      if ((gq & 1) == 0) {
        a0  += w0[k]*hv.x + w0[k+1]*hv.y + w0[k+2]*hv.z + w0[k+3]*hv.w;
        a1v += w1[k]*hv.x + w1[k+1]*hv.y + w1[k+2]*hv.z + w1[k+3]*hv.w;
      } else {
        b0 += w0[k]*hv.x + w0[k+1]*hv.y + w0[k+2]*hv.z + w0[k+3]*hv.w;
        b1 += w1[k]*hv.x + w1[k+1]*hv.y + w1[k+2]*hv.z + w1[k+3]*hv.w;
      }
    }
    h0 = fast_tanh(a0 + b0);
    h1 = fast_tanh(a1v + b1);
    h_lds[nxt][u0] = h0;
    if (m1) h_lds[nxt][u1] = h1;
    xp0 = xp0n; xp1 = xp1n;
  }

  float s = h0 * fw0 + (m1 ? h1 * fw1 : 0.f);
  #pragma unroll
  for (int off = 32; off > 0; off >>= 1) s += __shfl_down(s, off);
  if (l == 0) out[row] = 1.0f / (1.0f + __expf(-(s + fcb[0])));
}

// ---------------- host ----------------------------------------------------------
extern "C" void kernel_launch(void* const* d_in, const int* in_sizes, int n_in,
                              void* d_out, int out_size, void* d_ws, size_t ws_size,
                              hipStream_t stream) {
  const int*   x     = (const int*)  d_in[0];
  const float* table = (const float*)d_in[1];
  const float* Wih   = (const float*)d_in[2];
  const float* Whh   = (const float*)d_in[3];
  const float* bih   = (const float*)d_in[4];
  const float* bhh   = (const float*)d_in[5];
  const float* fcW   = (const float*)d_in[6];
  const float* fcb   = (const float*)d_in[7];
  float* out = (float*)d_out;

  unsigned char* ws = (unsigned char*)d_ws;

  if (ws_size >= WS_NEED) {
    unsigned short* WhhHi = (unsigned short*)ws;
    unsigned short* WhhLo = (unsigned short*)(ws + WHH_BYTES);
    float* Pt = (float*)(ws + P_OFF);
    prep_whh<<<(UP * KP + 255) / 256, 256, 0, stream>>>(Whh, WhhHi, WhhLo);
    proj_kernel<<<(VOCAB + 15) / 16, 128, 0, stream>>>(table, Wih, bih, bhh, Pt);
    rnn_mfma_kernel<<<NBLK, 256, 0, stream>>>(x, ws, fcW, fcb, out);
  } else {
    float* Pt = (float*)ws;
    proj_kernel<<<(VOCAB + 15) / 16, 128, 0, stream>>>(table, Wih, bih, bhh, Pt);
    rnn_wave_kernel<<<BATCH, 64, 0, stream>>>(x, Pt, Whh, fcW, fcb, out);
  }
}

// Round 6
// 374.608 us; speedup vs baseline: 1.1904x; 1.1904x over previous
//
#include <hip/hip_runtime.h>
#include <hip/hip_bf16.h>
#include <cstdint>

#define VOCAB  50001
#define EMBED  64
#define HIDDEN 100
#define TSTEPS 512
#define BATCH  2048

typedef short bf16x8 __attribute__((ext_vector_type(8)));
typedef float f32x4  __attribute__((ext_vector_type(4)));

constexpr int RB = 16;               // batch rows per block
constexpr int KP = 128;              // padded K (hidden) for MFMA
constexpr int UP = 112;              // padded units (M)
constexpr int NBLK = BATCH / RB;     // 128 blocks

constexpr size_t WHH_BYTES = (size_t)UP * KP * 2;      // 28672 per half
constexpr size_t P_OFF     = 2 * WHH_BYTES;            // 57344
constexpr size_t P_BYTES   = (size_t)VOCAB * HIDDEN * 4;
constexpr size_t WS_NEED   = P_OFF + P_BYTES;

__device__ __forceinline__ float fast_tanh(float x) {
  const float e = __expf(2.0f * x);
  return 1.0f - 2.0f * __builtin_amdgcn_rcpf(e + 1.0f);
}
__device__ __forceinline__ unsigned cvt_pk_bf16(float a, float b) {
  unsigned r;
  asm("v_cvt_pk_bf16_f32 %0, %1, %2" : "=v"(r) : "v"(a), "v"(b));
  return r;
}
__device__ __forceinline__ f32x4 zf4() { f32x4 z = {0.f, 0.f, 0.f, 0.f}; return z; }

#define MFMA16(A,B,C) __builtin_amdgcn_mfma_f32_16x16x32_bf16((A),(B),(C),0,0,0)

// ---------------- P[v][j] = W_ih[j,:]·table[v,:] + b_ih[j] + b_hh[j] -----------
__global__ __launch_bounds__(128) void proj_kernel(
    const float* __restrict__ table, const float* __restrict__ Wih,
    const float* __restrict__ bih, const float* __restrict__ bhh,
    float* __restrict__ P)
{
  constexpr int VPB = 16;
  __shared__ float e[VPB][EMBED];
  const int vbase = blockIdx.x * VPB;
  const int tid = threadIdx.x;
  #pragma unroll
  for (int r = 0; r < VPB * EMBED / 128; ++r) {
    const int el = tid + 128 * r;
    const int v  = vbase + (el >> 6);
    e[el >> 6][el & 63] = (v < VOCAB) ? table[(size_t)v * EMBED + (el & 63)] : 0.f;
  }
  __syncthreads();

  const int j = (tid < HIDDEN) ? tid : HIDDEN - 1;
  float w[EMBED];
  #pragma unroll
  for (int k = 0; k < EMBED; k += 4) {
    const float4 t4 = *reinterpret_cast<const float4*>(&Wih[j * EMBED + k]);
    w[k] = t4.x; w[k+1] = t4.y; w[k+2] = t4.z; w[k+3] = t4.w;
  }
  const float bias = bih[j] + bhh[j];

  for (int r = 0; r < VPB; ++r) {
    const int v = vbase + r;
    if (v >= VOCAB) break;
    float acc = bias;
    #pragma unroll
    for (int k = 0; k < EMBED; k += 4) {
      const float4 ev = *reinterpret_cast<const float4*>(&e[r][k]);
      acc += w[k]*ev.x + w[k+1]*ev.y + w[k+2]*ev.z + w[k+3]*ev.w;
    }
    if (tid < HIDDEN) P[(size_t)v * HIDDEN + tid] = acc;
  }
}

// ---------------- Whh -> split-bf16 padded [UP][KP] (hi, lo) -------------------
__global__ __launch_bounds__(256) void prep_whh(
    const float* __restrict__ Whh, unsigned short* __restrict__ hi,
    unsigned short* __restrict__ lo)
{
  const int i = blockIdx.x * 256 + threadIdx.x;
  if (i >= UP * KP) return;
  const int u = i >> 7, k = i & (KP - 1);
  const float v = (u < HIDDEN && k < HIDDEN) ? Whh[u * HIDDEN + k] : 0.f;
  const unsigned b = __float_as_uint(v);
  const unsigned h16 = (b + 0x7FFFu + ((b >> 16) & 1u)) >> 16;
  const float hf = __uint_as_float(h16 << 16);
  const float r = v - hf;
  const unsigned rb = __float_as_uint(r);
  const unsigned l16 = (rb + 0x7FFFu + ((rb >> 16) & 1u)) >> 16;
  hi[i] = (unsigned short)h16;
  lo[i] = (unsigned short)l16;
}

// ---------------- MFMA recurrence: 16 rows/block, 4 waves ----------------------
// G^T[UP][16] = W[UP][KP] x hT[KP][16] per step, W = Whi + Wlo (exact to 2^-18),
// h stored bf16 (hi only). Tiles -> waves {2,2,2,1}: mt0=2w, mt1=2w+1.
// Per wave per step: <=16 MFMAs = ~256 cyc of SIMD matrix issue.
__global__ __launch_bounds__(256, 1)
void rnn_mfma_kernel(const int* __restrict__ x, const unsigned char* __restrict__ ws,
                     const float* __restrict__ fcW, const float* __restrict__ fcb,
                     float* __restrict__ out)
{
  __shared__ __align__(16) unsigned char hbuf[2][4096]; // [buf][16 rows][128 k] bf16 (hi)
  __shared__ int idx_lds[TSTEPS][RB];
  __shared__ float red[64];

  const int tid = threadIdx.x;
  const int w   = tid >> 6;
  const int l   = tid & 63;
  const int row = l & 15;
  const int g   = l >> 4;
  const int row0 = blockIdx.x * RB;
  const unsigned swz = (unsigned)((row & 7) << 4);

  // zero h buffers (doubles as h0 = 0)
  {
    uint4* hz = reinterpret_cast<uint4*>(&hbuf[0][0]);
    #pragma unroll
    for (int i = 0; i < 2; ++i) hz[tid + 256 * i] = make_uint4(0u, 0u, 0u, 0u);
  }
  // stage x indices transposed: idx_lds[t][r]
  {
    const int r = tid >> 4, tl = tid & 15;
    const int* __restrict__ xr = x + (size_t)(row0 + r) * TSTEPS;
    for (int c = 0; c < TSTEPS / 16; ++c) {
      const int t = tl + 16 * c;
      idx_lds[t][r] = xr[t];
    }
  }

  const unsigned char* __restrict__ WH = ws;
  const unsigned char* __restrict__ WL = ws + WHH_BYTES;
  const float* __restrict__ Pb = reinterpret_cast<const float*>(ws + P_OFF);

  const int  mt0  = 2 * w;              // tiles {0,2,4,6}
  const bool has2 = (w < 3);
  const int  mt1  = has2 ? (2 * w + 1) : 0;   // tiles {1,3,5}

  // loop-invariant A fragments in registers (W split hi/lo)
  bf16x8 whi0[4], wlo0[4], whi1[4], wlo1[4];
  #pragma unroll
  for (int kt = 0; kt < 4; ++kt) {
    const unsigned off0 = (unsigned)(mt0 * 16 + row) * 256u + (unsigned)(kt * 64 + g * 16);
    whi0[kt] = *reinterpret_cast<const bf16x8*>(WH + off0);
    wlo0[kt] = *reinterpret_cast<const bf16x8*>(WL + off0);
    const unsigned off1 = (unsigned)(mt1 * 16 + row) * 256u + (unsigned)(kt * 64 + g * 16);
    whi1[kt] = *reinterpret_cast<const bf16x8*>(WH + off1);
    wlo1[kt] = *reinterpret_cast<const bf16x8*>(WL + off1);
  }

  const int useed0  = mt0 * 16 + g * 4;            // up to 108 on wave 3
  const int useed0c = (useed0 <= 96) ? useed0 : 96; // clamp P-col for pad units
  const int useed1  = mt1 * 16 + g * 4;            // <= 92, always valid

  __syncthreads();

  // seed prefetch (depth 2): SA for even steps, SB for odd
  f32x4 SA[2], SB[2];
  {
    const int x0 = idx_lds[0][row];
    const int x1 = idx_lds[1][row];
    SA[0] = *reinterpret_cast<const f32x4*>(Pb + (size_t)x0 * HIDDEN + useed0c);
    SB[0] = *reinterpret_cast<const f32x4*>(Pb + (size_t)x1 * HIDDEN + useed0c);
    SA[1] = has2 ? *reinterpret_cast<const f32x4*>(Pb + (size_t)x0 * HIDDEN + useed1) : zf4();
    SB[1] = has2 ? *reinterpret_cast<const f32x4*>(Pb + (size_t)x1 * HIDDEN + useed1) : zf4();
  }

  auto body = [&](int t, const unsigned char* hbR, unsigned char* hbW, f32x4 (&S)[2]) {
    // B fragments (h, bf16-hi), XOR-swizzled rows -> ~2-way conflicts
    bf16x8 bhi[4];
    #pragma unroll
    for (int kt = 0; kt < 4; ++kt) {
      const unsigned off = ((unsigned)(row * 256 + kt * 64 + g * 16)) ^ swz;
      bhi[kt] = *reinterpret_cast<const bf16x8*>(hbR + off);
    }
    // tile 0: 2 split products on independent accumulators
    f32x4 a1 = S[0], a3 = zf4();
    #pragma unroll
    for (int kt = 0; kt < 4; ++kt) {
      a1 = MFMA16(whi0[kt], bhi[kt], a1);
      a3 = MFMA16(wlo0[kt], bhi[kt], a3);
    }
    const f32x4 d0 = a1 + a3;
    f32x4 d1 = zf4();
    if (has2) {
      f32x4 c1 = S[1], c3 = zf4();
      #pragma unroll
      for (int kt = 0; kt < 4; ++kt) {
        c1 = MFMA16(whi1[kt], bhi[kt], c1);
        c3 = MFMA16(wlo1[kt], bhi[kt], c3);
      }
      d1 = c1 + c3;
    }
    // refill seeds for t+2 (2-step prefetch hides L3/HBM gather latency)
    {
      const int tn = (t + 2 < TSTEPS) ? t + 2 : TSTEPS - 1;
      const int xt = idx_lds[tn][row];
      S[0] = *reinterpret_cast<const f32x4*>(Pb + (size_t)xt * HIDDEN + useed0c);
      if (has2) S[1] = *reinterpret_cast<const f32x4*>(Pb + (size_t)xt * HIDDEN + useed1);
    }
    // tanh -> bf16 -> LDS
    {
      const unsigned ph01 = cvt_pk_bf16(fast_tanh(d0[0]), fast_tanh(d0[1]));
      const unsigned ph23 = cvt_pk_bf16(fast_tanh(d0[2]), fast_tanh(d0[3]));
      const unsigned off = ((unsigned)(row * 256 + useed0 * 2)) ^ swz;
      *reinterpret_cast<uint2*>(hbW + off) = make_uint2(ph01, ph23);
    }
    if (has2) {
      const unsigned ph01 = cvt_pk_bf16(fast_tanh(d1[0]), fast_tanh(d1[1]));
      const unsigned ph23 = cvt_pk_bf16(fast_tanh(d1[2]), fast_tanh(d1[3]));
      const unsigned off = ((unsigned)(row * 256 + useed1 * 2)) ^ swz;
      *reinterpret_cast<uint2*>(hbW + off) = make_uint2(ph01, ph23);
    }
    __syncthreads();
  };

  for (int t = 0; t < TSTEPS; t += 2) {
    body(t,     &hbuf[0][0], &hbuf[1][0], SA);
    body(t + 1, &hbuf[1][0], &hbuf[0][0], SB);
  }

  // FC + sigmoid (final h is in hbuf[0])
  if (w == 0) {
    const unsigned char* hbF = &hbuf[0][0];
    float part = 0.f;
    for (int i = 0; i < 25; ++i) {
      const int u = g * 25 + i;
      const unsigned off = ((unsigned)(row * 256 + u * 2)) ^ swz;
      const unsigned short vh = *reinterpret_cast<const unsigned short*>(hbF + off);
      const float hv = __uint_as_float((unsigned)vh << 16);
      part += hv * fcW[u];
    }
    red[l] = part;
  }
  __syncthreads();
  if (tid < RB) {
    const float s = red[tid] + red[tid + 16] + red[tid + 32] + red[tid + 48] + fcb[0];
    out[row0 + tid] = 1.0f / (1.0f + __expf(-s));
  }
}

// ---------------- fallback: exact fp32 wave kernel -----------------------------
__global__ __launch_bounds__(64)
__attribute__((amdgpu_waves_per_eu(2, 2)))
void rnn_wave_kernel(
    const int* __restrict__ x, const float* __restrict__ P,
    const float* __restrict__ Whh,
    const float* __restrict__ fcW, const float* __restrict__ fcb,
    float* __restrict__ out)
{
  __shared__ float h_lds[2][112];
  const int row = blockIdx.x;
  const int l = threadIdx.x;
  const int u0 = l;
  const bool m1 = (l < HIDDEN - 64);
  const int u1 = m1 ? (64 + l) : (HIDDEN - 1);

  float w0[HIDDEN], w1[HIDDEN];
  #pragma unroll
  for (int k = 0; k < HIDDEN; k += 4) {
    const float4 a = *reinterpret_cast<const float4*>(&Whh[u0 * HIDDEN + k]);
    w0[k] = a.x; w0[k+1] = a.y; w0[k+2] = a.z; w0[k+3] = a.w;
    const float4 b = *reinterpret_cast<const float4*>(&Whh[u1 * HIDDEN + k]);
    w1[k] = b.x; w1[k+1] = b.y; w1[k+2] = b.z; w1[k+3] = b.w;
  }
  const float fw0 = fcW[u0];
  const float fw1 = m1 ? fcW[u1] : 0.f;

  h_lds[0][l] = 0.f;
  h_lds[0][l + 48] = 0.f;

  const int* __restrict__ xrow = x + (size_t)row * TSTEPS;
  const int i0 = xrow[0];
  float xp0 = P[i0 * HIDDEN + u0];
  float xp1 = P[i0 * HIDDEN + u1];
  int i_nx = xrow[1];

  float h0 = 0.f, h1 = 0.f;
  for (int t = 0; t < TSTEPS; ++t) {
    const int cur = t & 1, nxt = cur ^ 1;
    const float* __restrict__ Prow = P + i_nx * HIDDEN;
    const float xp0n = Prow[u0];
    const float xp1n = Prow[u1];
    i_nx = (t + 2 < TSTEPS) ? xrow[t + 2] : 0;

    float a0 = xp0, b0 = 0.f, a1v = xp1, b1 = 0.f;
    const float4* __restrict__ hb = reinterpret_cast<const float4*>(&h_lds[cur][0]);
    #pragma unroll
    for (int gq = 0; gq < HIDDEN / 4; ++gq) {
      const float4 hv = hb[gq];
      const int k = 4 * gq;
      if ((gq & 1) == 0) {
        a0  += w0[k]*hv.x + w0[k+1]*hv.y + w0[k+2]*hv.z + w0[k+3]*hv.w;
        a1v += w1[k]*hv.x + w1[k+1]*hv.y + w1[k+2]*hv.z + w1[k+3]*hv.w;
      } else {
        b0 += w0[k]*hv.x + w0[k+1]*hv.y + w0[k+2]*hv.z + w0[k+3]*hv.w;
        b1 += w1[k]*hv.x + w1[k+1]*hv.y + w1[k+2]*hv.z + w1[k+3]*hv.w;
      }
    }
    h0 = fast_tanh(a0 + b0);
    h1 = fast_tanh(a1v + b1);
    h_lds[nxt][u0] = h0;
    if (m1) h_lds[nxt][u1] = h1;
    xp0 = xp0n; xp1 = xp1n;
  }

  float s = h0 * fw0 + (m1 ? h1 * fw1 : 0.f);
  #pragma unroll
  for (int off = 32; off > 0; off >>= 1) s += __shfl_down(s, off);
  if (l == 0) out[row] = 1.0f / (1.0f + __expf(-(s + fcb[0])));
}

// ---------------- host ----------------------------------------------------------
extern "C" void kernel_launch(void* const* d_in, const int* in_sizes, int n_in,
                              void* d_out, int out_size, void* d_ws, size_t ws_size,
                              hipStream_t stream) {
  const int*   x     = (const int*)  d_in[0];
  const float* table = (const float*)d_in[1];
  const float* Wih   = (const float*)d_in[2];
  const float* Whh   = (const float*)d_in[3];
  const float* bih   = (const float*)d_in[4];
  const float* bhh   = (const float*)d_in[5];
  const float* fcW   = (const float*)d_in[6];
  const float* fcb   = (const float*)d_in[7];
  float* out = (float*)d_out;

  unsigned char* ws = (unsigned char*)d_ws;

  if (ws_size >= WS_NEED) {
    unsigned short* WhhHi = (unsigned short*)ws;
    unsigned short* WhhLo = (unsigned short*)(ws + WHH_BYTES);
    float* Pt = (float*)(ws + P_OFF);
    prep_whh<<<(UP * KP + 255) / 256, 256, 0, stream>>>(Whh, WhhHi, WhhLo);
    proj_kernel<<<(VOCAB + 15) / 16, 128, 0, stream>>>(table, Wih, bih, bhh, Pt);
    rnn_mfma_kernel<<<NBLK, 256, 0, stream>>>(x, ws, fcW, fcb, out);
  } else {
    float* Pt = (float*)ws;
    proj_kernel<<<(VOCAB + 15) / 16, 128, 0, stream>>>(table, Wih, bih, bhh, Pt);
    rnn_wave_kernel<<<BATCH, 64, 0, stream>>>(x, Pt, Whh, fcW, fcb, out);
  }
}

// Round 7
// 280.346 us; speedup vs baseline: 1.5907x; 1.3362x over previous
//
#include <hip/hip_runtime.h>
#include <hip/hip_bf16.h>
#include <cstdint>

#define VOCAB  50001
#define EMBED  64
#define HIDDEN 100
#define TSTEPS 512
#define BATCH  2048

typedef short bf16x8 __attribute__((ext_vector_type(8)));
typedef float f32x4  __attribute__((ext_vector_type(4)));

constexpr int RB = 16;               // batch rows per block
constexpr int KP = 128;              // padded K (hidden) for MFMA
constexpr int UP = 128;              // padded units (M): 8 tiles, 1 per wave
constexpr int NBLK = BATCH / RB;     // 128 blocks

constexpr size_t WHH_BYTES = (size_t)UP * KP * 2;      // 32768 per half
constexpr size_t P_OFF     = 2 * WHH_BYTES;            // 65536
constexpr size_t P_BYTES   = (size_t)VOCAB * HIDDEN * 4;
constexpr size_t WS_NEED   = P_OFF + P_BYTES;

__device__ __forceinline__ float fast_tanh(float x) {
  const float e = __expf(2.0f * x);
  return 1.0f - 2.0f * __builtin_amdgcn_rcpf(e + 1.0f);
}
__device__ __forceinline__ unsigned cvt_pk_bf16(float a, float b) {
  unsigned r;
  asm("v_cvt_pk_bf16_f32 %0, %1, %2" : "=v"(r) : "v"(a), "v"(b));
  return r;
}
__device__ __forceinline__ f32x4 zf4() { f32x4 z = {0.f, 0.f, 0.f, 0.f}; return z; }

#define MFMA16(A,B,C) __builtin_amdgcn_mfma_f32_16x16x32_bf16((A),(B),(C),0,0,0)

// ---------------- P[v][j] = W_ih[j,:]·table[v,:] + b_ih[j] + b_hh[j] -----------
__global__ __launch_bounds__(128) void proj_kernel(
    const float* __restrict__ table, const float* __restrict__ Wih,
    const float* __restrict__ bih, const float* __restrict__ bhh,
    float* __restrict__ P)
{
  constexpr int VPB = 16;
  __shared__ float e[VPB][EMBED];
  const int vbase = blockIdx.x * VPB;
  const int tid = threadIdx.x;
  #pragma unroll
  for (int r = 0; r < VPB * EMBED / 128; ++r) {
    const int el = tid + 128 * r;
    const int v  = vbase + (el >> 6);
    e[el >> 6][el & 63] = (v < VOCAB) ? table[(size_t)v * EMBED + (el & 63)] : 0.f;
  }
  __syncthreads();

  const int j = (tid < HIDDEN) ? tid : HIDDEN - 1;
  float w[EMBED];
  #pragma unroll
  for (int k = 0; k < EMBED; k += 4) {
    const float4 t4 = *reinterpret_cast<const float4*>(&Wih[j * EMBED + k]);
    w[k] = t4.x; w[k+1] = t4.y; w[k+2] = t4.z; w[k+3] = t4.w;
  }
  const float bias = bih[j] + bhh[j];

  for (int r = 0; r < VPB; ++r) {
    const int v = vbase + r;
    if (v >= VOCAB) break;
    float acc = bias;
    #pragma unroll
    for (int k = 0; k < EMBED; k += 4) {
      const float4 ev = *reinterpret_cast<const float4*>(&e[r][k]);
      acc += w[k]*ev.x + w[k+1]*ev.y + w[k+2]*ev.z + w[k+3]*ev.w;
    }
    if (tid < HIDDEN) P[(size_t)v * HIDDEN + tid] = acc;
  }
}

// ---------------- Whh -> split-bf16 padded [UP][KP] (hi, lo) -------------------
__global__ __launch_bounds__(256) void prep_whh(
    const float* __restrict__ Whh, unsigned short* __restrict__ hi,
    unsigned short* __restrict__ lo)
{
  const int i = blockIdx.x * 256 + threadIdx.x;
  if (i >= UP * KP) return;
  const int u = i >> 7, k = i & (KP - 1);
  const float v = (u < HIDDEN && k < HIDDEN) ? Whh[u * HIDDEN + k] : 0.f;
  const unsigned b = __float_as_uint(v);
  const unsigned h16 = (b + 0x7FFFu + ((b >> 16) & 1u)) >> 16;
  const float hf = __uint_as_float(h16 << 16);
  const float r = v - hf;
  const unsigned rb = __float_as_uint(r);
  const unsigned l16 = (rb + 0x7FFFu + ((rb >> 16) & 1u)) >> 16;
  hi[i] = (unsigned short)h16;
  lo[i] = (unsigned short)l16;
}

// ---------------- MFMA recurrence: 16 rows/block, 8 waves, 1 tile/wave ---------
// G^T[UP][16] = W[UP][KP] x hT[KP][16] per step, W = Whi + Wlo (exact to 2^-18),
// h stored bf16. 8 waves x 8 MFMAs/step; 2 waves/SIMD so one wave's MFMA
// overlaps the other's LDS/tanh/write. Wave 7's tile is pure padding (W rows
// 112-127 = 0): its h outputs multiply zero W-columns -> harmless, no branches.
__global__ __launch_bounds__(512, 1)
void rnn_mfma_kernel(const int* __restrict__ x, const unsigned char* __restrict__ ws,
                     const float* __restrict__ fcW, const float* __restrict__ fcb,
                     float* __restrict__ out)
{
  __shared__ __align__(16) unsigned char hbuf[2][4096]; // [buf][16 rows][128 k] bf16
  __shared__ int idx_lds[TSTEPS][RB];
  __shared__ float red[64];

  const int tid = threadIdx.x;
  const int w   = tid >> 6;             // 0..7, tile index
  const int l   = tid & 63;
  const int row = l & 15;
  const int g   = l >> 4;
  const int row0 = blockIdx.x * RB;
  const unsigned swz = (unsigned)((row & 7) << 4);

  // zero h buffers (doubles as h0 = 0): 512 uint4 = 8192 B
  reinterpret_cast<uint4*>(&hbuf[0][0])[tid] = make_uint4(0u, 0u, 0u, 0u);

  // stage x indices transposed: idx_lds[t][r]; coalesced per row
  {
    const int r = tid >> 5, tl = tid & 31;
    const int* __restrict__ xr = x + (size_t)(row0 + r) * TSTEPS;
    #pragma unroll
    for (int c = 0; c < TSTEPS / 32; ++c) {
      const int t = tl + 32 * c;
      idx_lds[t][r] = xr[t];
    }
  }

  const unsigned char* __restrict__ WH = ws;
  const unsigned char* __restrict__ WL = ws + WHH_BYTES;
  const float* __restrict__ Pb = reinterpret_cast<const float*>(ws + P_OFF);

  // loop-invariant A fragments in registers (W split hi/lo), tile mt = w
  bf16x8 whi[4], wlo[4];
  #pragma unroll
  for (int kt = 0; kt < 4; ++kt) {
    const unsigned off = (unsigned)(w * 16 + row) * 256u + (unsigned)(kt * 64 + g * 16);
    whi[kt] = *reinterpret_cast<const bf16x8*>(WH + off);
    wlo[kt] = *reinterpret_cast<const bf16x8*>(WL + off);
  }

  const int useed  = w * 16 + g * 4;                // unit base for D frag
  const int useedc = (useed <= 96) ? useed : 96;    // clamp P col for pad units

  __syncthreads();

  // seed prefetch (depth 2): SA for even steps, SB for odd
  f32x4 SA, SB;
  {
    const int x0 = idx_lds[0][row];
    const int x1 = idx_lds[1][row];
    SA = *reinterpret_cast<const f32x4*>(Pb + (size_t)x0 * HIDDEN + useedc);
    SB = *reinterpret_cast<const f32x4*>(Pb + (size_t)x1 * HIDDEN + useedc);
  }

  auto body = [&](int t, const unsigned char* hbR, unsigned char* hbW, f32x4 &S) {
    // B fragments (h bf16), XOR-swizzled rows -> ~2-way conflicts
    bf16x8 bhi[4];
    #pragma unroll
    for (int kt = 0; kt < 4; ++kt) {
      const unsigned off = ((unsigned)(row * 256 + kt * 64 + g * 16)) ^ swz;
      bhi[kt] = *reinterpret_cast<const bf16x8*>(hbR + off);
    }
    // 2 split products on independent accumulators: 8 MFMAs
    f32x4 a1 = S, a3 = zf4();
    #pragma unroll
    for (int kt = 0; kt < 4; ++kt) {
      a1 = MFMA16(whi[kt], bhi[kt], a1);
      a3 = MFMA16(wlo[kt], bhi[kt], a3);
    }
    const f32x4 d0 = a1 + a3;
    // refill seed for t+2 (prefetch hides L2/L3 gather latency)
    {
      const int tn = (t + 2 < TSTEPS) ? t + 2 : TSTEPS - 1;
      const int xt = idx_lds[tn][row];
      S = *reinterpret_cast<const f32x4*>(Pb + (size_t)xt * HIDDEN + useedc);
    }
    // tanh -> bf16 -> LDS
    {
      const unsigned ph01 = cvt_pk_bf16(fast_tanh(d0[0]), fast_tanh(d0[1]));
      const unsigned ph23 = cvt_pk_bf16(fast_tanh(d0[2]), fast_tanh(d0[3]));
      const unsigned off = ((unsigned)(row * 256 + useed * 2)) ^ swz;
      *reinterpret_cast<uint2*>(hbW + off) = make_uint2(ph01, ph23);
    }
    __syncthreads();
  };

  for (int t = 0; t < TSTEPS; t += 2) {
    body(t,     &hbuf[0][0], &hbuf[1][0], SA);
    body(t + 1, &hbuf[1][0], &hbuf[0][0], SB);
  }

  // FC + sigmoid (final h is in hbuf[0])
  if (w == 0) {
    const unsigned char* hbF = &hbuf[0][0];
    float part = 0.f;
    for (int i = 0; i < 25; ++i) {
      const int u = g * 25 + i;
      const unsigned off = ((unsigned)(row * 256 + u * 2)) ^ swz;
      const unsigned short vh = *reinterpret_cast<const unsigned short*>(hbF + off);
      const float hv = __uint_as_float((unsigned)vh << 16);
      part += hv * fcW[u];
    }
    red[l] = part;
  }
  __syncthreads();
  if (tid < RB) {
    const float s = red[tid] + red[tid + 16] + red[tid + 32] + red[tid + 48] + fcb[0];
    out[row0 + tid] = 1.0f / (1.0f + __expf(-s));
  }
}

// ---------------- fallback: exact fp32 wave kernel -----------------------------
__global__ __launch_bounds__(64)
__attribute__((amdgpu_waves_per_eu(2, 2)))
void rnn_wave_kernel(
    const int* __restrict__ x, const float* __restrict__ P,
    const float* __restrict__ Whh,
    const float* __restrict__ fcW, const float* __restrict__ fcb,
    float* __restrict__ out)
{
  __shared__ float h_lds[2][112];
  const int row = blockIdx.x;
  const int l = threadIdx.x;
  const int u0 = l;
  const bool m1 = (l < HIDDEN - 64);
  const int u1 = m1 ? (64 + l) : (HIDDEN - 1);

  float w0[HIDDEN], w1[HIDDEN];
  #pragma unroll
  for (int k = 0; k < HIDDEN; k += 4) {
    const float4 a = *reinterpret_cast<const float4*>(&Whh[u0 * HIDDEN + k]);
    w0[k] = a.x; w0[k+1] = a.y; w0[k+2] = a.z; w0[k+3] = a.w;
    const float4 b = *reinterpret_cast<const float4*>(&Whh[u1 * HIDDEN + k]);
    w1[k] = b.x; w1[k+1] = b.y; w1[k+2] = b.z; w1[k+3] = b.w;
  }
  const float fw0 = fcW[u0];
  const float fw1 = m1 ? fcW[u1] : 0.f;

  h_lds[0][l] = 0.f;
  h_lds[0][l + 48] = 0.f;

  const int* __restrict__ xrow = x + (size_t)row * TSTEPS;
  const int i0 = xrow[0];
  float xp0 = P[i0 * HIDDEN + u0];
  float xp1 = P[i0 * HIDDEN + u1];
  int i_nx = xrow[1];

  float h0 = 0.f, h1 = 0.f;
  for (int t = 0; t < TSTEPS; ++t) {
    const int cur = t & 1, nxt = cur ^ 1;
    const float* __restrict__ Prow = P + i_nx * HIDDEN;
    const float xp0n = Prow[u0];
    const float xp1n = Prow[u1];
    i_nx = (t + 2 < TSTEPS) ? xrow[t + 2] : 0;

    float a0 = xp0, b0 = 0.f, a1v = xp1, b1 = 0.f;
    const float4* __restrict__ hb = reinterpret_cast<const float4*>(&h_lds[cur][0]);
    #pragma unroll
    for (int gq = 0; gq < HIDDEN / 4; ++gq) {
      const float4 hv = hb[gq];
      const int k = 4 * gq;
      if ((gq & 1) == 0) {
        a0  += w0[k]*hv.x + w0[k+1]*hv.y + w0[k+2]*hv.z + w0[k+3]*hv.w;
        a1v += w1[k]*hv.x + w1[k+1]*hv.y + w1[k+2]*hv.z + w1[k+3]*hv.w;
      } else {
        b0 += w0[k]*hv.x + w0[k+1]*hv.y + w0[k+2]*hv.z + w0[k+3]*hv.w;
        b1 += w1[k]*hv.x + w1[k+1]*hv.y + w1[k+2]*hv.z + w1[k+3]*hv.w;
      }
    }
    h0 = fast_tanh(a0 + b0);
    h1 = fast_tanh(a1v + b1);
    h_lds[nxt][u0] = h0;
    if (m1) h_lds[nxt][u1] = h1;
    xp0 = xp0n; xp1 = xp1n;
  }

  float s = h0 * fw0 + (m1 ? h1 * fw1 : 0.f);
  #pragma unroll
  for (int off = 32; off > 0; off >>= 1) s += __shfl_down(s, off);
  if (l == 0) out[row] = 1.0f / (1.0f + __expf(-(s + fcb[0])));
}

// ---------------- host ----------------------------------------------------------
extern "C" void kernel_launch(void* const* d_in, const int* in_sizes, int n_in,
                              void* d_out, int out_size, void* d_ws, size_t ws_size,
                              hipStream_t stream) {
  const int*   x     = (const int*)  d_in[0];
  const float* table = (const float*)d_in[1];
  const float* Wih   = (const float*)d_in[2];
  const float* Whh   = (const float*)d_in[3];
  const float* bih   = (const float*)d_in[4];
  const float* bhh   = (const float*)d_in[5];
  const float* fcW   = (const float*)d_in[6];
  const float* fcb   = (const float*)d_in[7];
  float* out = (float*)d_out;

  unsigned char* ws = (unsigned char*)d_ws;

  if (ws_size >= WS_NEED) {
    unsigned short* WhhHi = (unsigned short*)ws;
    unsigned short* WhhLo = (unsigned short*)(ws + WHH_BYTES);
    float* Pt = (float*)(ws + P_OFF);
    prep_whh<<<(UP * KP + 255) / 256, 256, 0, stream>>>(Whh, WhhHi, WhhLo);
    proj_kernel<<<(VOCAB + 15) / 16, 128, 0, stream>>>(table, Wih, bih, bhh, Pt);
    rnn_mfma_kernel<<<NBLK, 512, 0, stream>>>(x, ws, fcW, fcb, out);
  } else {
    float* Pt = (float*)ws;
    proj_kernel<<<(VOCAB + 15) / 16, 128, 0, stream>>>(table, Wih, bih, bhh, Pt);
    rnn_wave_kernel<<<BATCH, 64, 0, stream>>>(x, Pt, Whh, fcW, fcb, out);
  }
}